// Round 5
// baseline (247.958 us; speedup 1.0000x reference)
//
#include <hip/hip_runtime.h>

// LengthRegulator: B=32, T=512, D=384, ML=4096 (fixed by setup_inputs).
// out[b,f,:] = (f < total_b) ? x[b, clip(searchsorted(cum_b, f, 'right'),0,T-1), :] : 0
// mel_pos[b,f] = (f < total_b) ? f+1 : 0  (written as FLOAT values; d_out is
// one flat float32 buffer).
//
// Round 5: two-kernel split. Kernel A (32 blocks) does the per-batch scan +
// searchsorted ONCE, writing tok[b][f] (-1 = invalid) and total[b] into d_ws
// plus the mel output. Kernel B (2048 blocks) is a barrier-free, LDS-free
// streaming gather-copy with nontemporal stores. Removes the 2048x-redundant
// 16-barrier scan prologue from the hot kernel and shortens the per-store
// dependency chain.

typedef float v4f __attribute__((ext_vector_type(4)));

constexpr int B  = 32;
constexpr int T  = 512;
constexpr int D  = 384;
constexpr int ML = 4096;
constexpr int D4 = D / 4;                    // 96 float4 per row
constexpr int FPB = 64;                      // frames per block (kernel B)
constexpr int BLOCKS_PER_BATCH = ML / FPB;   // 64
constexpr int NT = 256;                      // threads per block
constexpr int ITERS = FPB * D4 / NT;         // 24 float4 stores per thread
constexpr int NXCD = 8;

// ---------------- Kernel A: per-batch scan + searchsorted ----------------
__global__ __launch_bounds__(NT) void lr_scan(
        const int* __restrict__ dur,       // [B, T]
        int*       __restrict__ tok_ws,    // [B, ML]
        int*       __restrict__ total_ws,  // [B]
        float*     __restrict__ mel)       // [B, ML]
{
    __shared__ int s_cum[T];
    __shared__ int s_part[NT];

    const int b   = blockIdx.x;
    const int tid = threadIdx.x;

    const int d0 = dur[b * T + 2 * tid];
    const int d1 = dur[b * T + 2 * tid + 1];
    const int pair = d0 + d1;
    s_part[tid] = pair;
    __syncthreads();
    int val = pair;
    #pragma unroll
    for (int off = 1; off < NT; off <<= 1) {
        int t = (tid >= off) ? s_part[tid - off] : 0;
        __syncthreads();
        val += t;
        s_part[tid] = val;
        __syncthreads();
    }
    const int excl = val - pair;
    s_cum[2 * tid]     = excl + d0;
    s_cum[2 * tid + 1] = excl + pair;
    __syncthreads();
    const int total = s_cum[T - 1];
    if (tid == 0) total_ws[b] = total;

    // searchsorted(side='right') for all ML frames; 16 frames per thread.
    #pragma unroll
    for (int j = 0; j < ML / NT; ++j) {
        const int f = tid + NT * j;
        int lo = 0, hi = T;
        while (lo < hi) {
            const int mid = (lo + hi) >> 1;
            if (s_cum[mid] <= f) lo = mid + 1; else hi = mid;
        }
        const int tok = (lo < T - 1) ? lo : (T - 1);
        const bool valid = f < total;
        tok_ws[b * ML + f] = valid ? tok : -1;
        mel[b * ML + f]    = valid ? (float)(f + 1) : 0.0f;
    }
}

// ---------------- Kernel B: barrier-free streaming gather-copy ----------------
__global__ __launch_bounds__(NT) void lr_copy(
        const v4f* __restrict__ x,         // [B, T, D4]
        const int* __restrict__ tok_ws,    // [B, ML]
        const int* __restrict__ total_ws,  // [B]
        v4f*       __restrict__ out4)      // [B, ML, D4]
{
    // XCD-locality swizzle (perf heuristic only).
    const int i_blk  = blockIdx.x;
    const int xcd    = i_blk & (NXCD - 1);
    const int j      = i_blk >> 3;
    const int b      = xcd + NXCD * (j >> 6);
    const int fchunk = j & (BLOCKS_PER_BATCH - 1);
    const int f0     = fchunk * FPB;
    const int tid    = threadIdx.x;

    const int total = total_ws[b];
    const v4f zero4 = (v4f){0.f, 0.f, 0.f, 0.f};
    v4f* op = out4 + ((size_t)b * ML + f0) * D4 + tid;

    if (f0 >= total) {                     // fully-invalid chunk: stream zeros
        #pragma unroll
        for (int k = 0; k < ITERS; ++k) {
            __builtin_nontemporal_store(zero4, op);
            op += NT;
        }
        return;
    }

    const int* tw = tok_ws + b * ML + f0;  // 64 ints, L1-broadcast reads
    const v4f* xb = x + (size_t)b * T * D4;
    int lf = tid / D4;
    int c  = tid - lf * D4;
    #pragma unroll
    for (int k = 0; k < ITERS; ++k) {
        const int tok = tw[lf];
        v4f v = zero4;
        if (tok >= 0) v = xb[tok * D4 + c];
        __builtin_nontemporal_store(v, op);
        op += NT;
        lf += 2; c += NT - 2 * D4;
        if (c >= D4) { c -= D4; ++lf; }
    }
}

extern "C" void kernel_launch(void* const* d_in, const int* in_sizes, int n_in,
                              void* d_out, int out_size, void* d_ws, size_t ws_size,
                              hipStream_t stream) {
    const v4f* x   = (const v4f*)d_in[0];
    const int* dur = (const int*)d_in[1];
    float* outf = (float*)d_out;
    float* mel  = outf + (size_t)B * ML * D;    // mel_pos region (float values)

    int* tok_ws   = (int*)d_ws;                 // B*ML ints = 512 KB
    int* total_ws = tok_ws + (size_t)B * ML;    // B ints

    lr_scan<<<dim3(B), dim3(NT), 0, stream>>>(dur, tok_ws, total_ws, mel);
    lr_copy<<<dim3(B * BLOCKS_PER_BATCH), dim3(NT), 0, stream>>>(
        x, tok_ws, total_ws, (v4f*)outf);
}

// Round 6
// 233.338 us; speedup vs baseline: 1.0627x; 1.0627x over previous
//
#include <hip/hip_runtime.h>

// LengthRegulator: B=32, T=512, D=384, ML=4096 (fixed by setup_inputs).
// out[b,f,:] = (f < total_b) ? x[b, clip(searchsorted(cum_b, f, 'right'),0,T-1), :] : 0
// mel_pos[b,f] = (f < total_b) ? f+1 : 0  (written as FLOAT values; d_out is
// one flat float32 buffer).
//
// Round 6: revert to the best measured config (round 4). Single kernel:
// per-block LDS scan + binary search + nontemporal streaming gather-copy,
// XCD-aware swizzle. Rounds 2-5 showed all structural variants (NT vs plain
// stores, FPB 64/128, prologue split) are neutral within ±8 us noise; the
// timed window is dominated by fixed harness poison-fills (~175 us) and the
// kernel itself sits at the ~36 us write-BW floor (202 MB @ ~6.3 TB/s).

typedef float v4f __attribute__((ext_vector_type(4)));

constexpr int B  = 32;
constexpr int T  = 512;
constexpr int D  = 384;
constexpr int ML = 4096;
constexpr int D4 = D / 4;                    // 96 float4 per row
constexpr int FPB = 64;                      // frames per block
constexpr int BLOCKS_PER_BATCH = ML / FPB;   // 64
constexpr int NT = 256;                      // threads per block
constexpr int ITERS = FPB * D4 / NT;         // 24 float4 stores per thread
constexpr int NXCD = 8;

__global__ __launch_bounds__(NT) void lr_kernel(
        const v4f* __restrict__ x,         // [B, T, D4]
        const int* __restrict__ dur,       // [B, T]
        v4f*       __restrict__ out4,      // [B, ML, D4]
        float*     __restrict__ mel)       // [B, ML]
{
    __shared__ int s_cum[T];
    __shared__ int s_tok[FPB];
    __shared__ int s_part[NT];

    // XCD-locality swizzle: xcd = i&7 (HW round-robin heuristic; perf-only).
    const int i_blk   = blockIdx.x;
    const int xcd     = i_blk & (NXCD - 1);
    const int j       = i_blk >> 3;                      // [0, 256)
    const int b       = xcd + NXCD * (j >> 6);           // [0, 32)
    const int fchunk  = j & (BLOCKS_PER_BATCH - 1);      // [0, 64)
    const int f0      = fchunk * FPB;
    const int tid     = threadIdx.x;

    // ---- cumsum(duration[b]) into LDS (each thread owns 2 elements) ----
    const int d0 = dur[b * T + 2 * tid];
    const int d1 = dur[b * T + 2 * tid + 1];
    const int pair = d0 + d1;
    s_part[tid] = pair;
    __syncthreads();
    int val = pair;
    #pragma unroll
    for (int off = 1; off < NT; off <<= 1) {
        int t = (tid >= off) ? s_part[tid - off] : 0;
        __syncthreads();
        val += t;
        s_part[tid] = val;
        __syncthreads();
    }
    const int excl = val - pair;          // exclusive scan of pair-sums
    s_cum[2 * tid]     = excl + d0;
    s_cum[2 * tid + 1] = excl + pair;
    __syncthreads();
    const int total = s_cum[T - 1];

    const v4f zero4 = (v4f){0.f, 0.f, 0.f, 0.f};
    v4f* op = out4 + ((size_t)b * ML + f0) * D4 + tid;

    // Fully-invalid chunk: pure zero streaming, no search, no gather.
    if (f0 >= total) {
        if (tid < FPB) mel[b * ML + f0 + tid] = 0.0f;
        #pragma unroll
        for (int k = 0; k < ITERS; ++k) {
            __builtin_nontemporal_store(zero4, op);
            op += NT;
        }
        return;
    }

    // ---- token index for this block's FPB frames (binary search in LDS) ----
    if (tid < FPB) {
        const int f = f0 + tid;
        int lo = 0, hi = T;               // searchsorted(side='right')
        while (lo < hi) {
            const int mid = (lo + hi) >> 1;
            if (s_cum[mid] <= f) lo = mid + 1; else hi = mid;
        }
        const int tok = (lo < T - 1) ? lo : (T - 1);
        s_tok[tid] = (f < total) ? tok : -1;
        mel[b * ML + f] = (f < total) ? (float)(f + 1) : 0.0f;
    }
    __syncthreads();

    // ---- coalesced float4 copy: FPB*D4 = 6144 vec4 per block ----
    const v4f* xb = x + (size_t)b * T * D4;
    int lf = tid / D4;                    // one divide, then incremental
    int c  = tid - lf * D4;
    #pragma unroll
    for (int k = 0; k < ITERS; ++k) {
        const int tok = s_tok[lf];
        v4f v = zero4;
        if (tok >= 0) v = xb[tok * D4 + c];
        __builtin_nontemporal_store(v, op);
        op += NT;
        lf += 2; c += NT - 2 * D4;        // advance linear index by NT=256
        if (c >= D4) { c -= D4; ++lf; }
    }
}

extern "C" void kernel_launch(void* const* d_in, const int* in_sizes, int n_in,
                              void* d_out, int out_size, void* d_ws, size_t ws_size,
                              hipStream_t stream) {
    const v4f* x    = (const v4f*)d_in[0];
    const int* dur  = (const int*)d_in[1];
    float* outf = (float*)d_out;
    float* mel  = outf + (size_t)B * ML * D;   // mel_pos region, float values

    dim3 grid(B * BLOCKS_PER_BATCH);
    dim3 block(NT);
    lr_kernel<<<grid, block, 0, stream>>>(x, dur, (v4f*)outf, mel);
}